// Round 2
// baseline (385.120 us; speedup 1.0000x reference)
//
#include <hip/hip_runtime.h>
#include <hip/hip_bf16.h>

#define N_NODES 10000
#define N_EDGES 320000
#define HDIM    256
#define NCLS    40

typedef __attribute__((ext_vector_type(8))) short short8;
typedef __attribute__((ext_vector_type(4))) float floatx4;
typedef unsigned long long ull;
typedef unsigned short ushort;

__device__ __forceinline__ float bf2f(ushort u) {
    union { unsigned int i; float f; } v; v.i = ((unsigned int)u) << 16; return v.f;
}
__device__ __forceinline__ ushort f2bf(float f) {
    __hip_bfloat16 h = __float2bfloat16(f);
    return *reinterpret_cast<ushort*>(&h);
}

// ---------------- runtime dtype detection (device-side, deterministic) ----------------
// flags[0] = 1 if float tensors are fp32, 0 if bf16
// flags[1] = 1 if edge_index is int64, 0 if int32

__global__ void detect_kernel(const void* x, const void* ei, int* flags) {
    if (threadIdx.x != 0 || blockIdx.x != 0) return;
    const ushort* u = (const ushort*)x;
    int bad = 0;
    for (int k = 0; k < 64; ++k) {
        int e = (u[2 * k] >> 7) & 0xFF;        // even ushort = fp32 low-mantissa (uniform) or a bf16 value
        if (e < 100 || e > 140) bad++;         // bf16 of N(0,1): exp always in [100,140]
    }
    flags[0] = (bad >= 8) ? 1 : 0;
    const int* ii = (const int*)ei;
    int odd_or = 0;
    for (int k = 0; k < 64; ++k) odd_or |= ii[2 * k + 1];  // int64 high words are all 0
    flags[1] = (odd_or == 0) ? 1 : 0;
}

// ---------------- convert float tensor (fp32 or bf16 in) -> bf16 out ----------------

__global__ void cvt_kernel(const void* __restrict__ in, ushort* __restrict__ out,
                           int n, const int* __restrict__ flags) {
    int i = blockIdx.x * 256 + threadIdx.x;
    if (i >= n) return;
    if (flags[0]) out[i] = f2bf(((const float*)in)[i]);
    else          out[i] = ((const ushort*)in)[i];
}

// ---------------- extract edges (int32 or int64 in) -> clean int32, range-clamped ----------------

__global__ void edges_kernel(const void* __restrict__ ei, const int* __restrict__ flags,
                             int* __restrict__ src, int* __restrict__ dst) {
    int e = blockIdx.x * 256 + threadIdx.x;
    if (e >= N_EDGES) return;
    const int* ii = (const int*)ei;
    int s, d;
    if (flags[1]) { s = ii[2 * e]; d = ii[2 * (N_EDGES + e)]; }
    else          { s = ii[e];     d = ii[N_EDGES + e]; }
    src[e] = ((unsigned)s < N_NODES) ? s : 0;
    dst[e] = ((unsigned)d < N_NODES) ? d : 0;
}

// ---------------- CSR build ----------------

__global__ void zero_cnt_kernel(int* cnt) {
    int i = blockIdx.x * 256 + threadIdx.x;
    if (i < N_NODES) cnt[i] = 0;
}

__global__ void count_kernel(const int* __restrict__ dst, int* __restrict__ cnt) {
    int e = blockIdx.x * 256 + threadIdx.x;
    if (e < N_EDGES) atomicAdd(&cnt[dst[e]], 1);
}

__global__ void dinv_kernel(const int* __restrict__ cnt, float* __restrict__ dinv) {
    int i = blockIdx.x * 256 + threadIdx.x;
    if (i < N_NODES) dinv[i] = rsqrtf((float)cnt[i] + 1.0f);  // +1 self loop
}

__global__ __launch_bounds__(1024)
void scan_kernel(const int* __restrict__ cnt, int* __restrict__ offs, int* __restrict__ woff) {
    __shared__ int part[1024];
    const int t = threadIdx.x;
    const int CH = (N_NODES + 1023) / 1024;  // 10
    const int base = t * CH;
    int s = 0;
    for (int j = 0; j < CH; ++j) {
        int i = base + j;
        if (i < N_NODES) s += cnt[i];
    }
    part[t] = s;
    __syncthreads();
    for (int off = 1; off < 1024; off <<= 1) {
        int v = 0;
        if (t >= off) v = part[t - off];
        __syncthreads();
        part[t] += v;
        __syncthreads();
    }
    int run = (t == 0) ? 0 : part[t - 1];
    for (int j = 0; j < CH; ++j) {
        int i = base + j;
        if (i < N_NODES) {
            offs[i] = run;
            woff[i] = run;
            run += cnt[i];
        }
    }
}

__global__ void fill_kernel(const int* __restrict__ src, const int* __restrict__ dst,
                            int* __restrict__ woff, int* __restrict__ csr) {
    int e = blockIdx.x * 256 + threadIdx.x;
    if (e < N_EDGES) {
        int d = dst[e];
        int p = atomicAdd(&woff[d], 1);
        csr[p] = src[e];
    }
}

// ---------------- GEMM: T[r][c] = (sum_k A[r][k] * W[k][c]) * dinv[r] ----------------
// A: N x 256 bf16.  W: 256 x DOUT bf16.  T: bf16 (F32OUT=0) or fp32 (F32OUT=1).

template <int DOUT, int F32OUT>
__global__ __launch_bounds__(256)
void gemm_kernel(const ushort* __restrict__ A,
                 const ushort* __restrict__ W,
                 const float* __restrict__ dinv,
                 void* __restrict__ T) {
    const int lane = threadIdx.x & 63;
    const int wave = threadIdx.x >> 6;
    const int m = lane & 15;
    const int quad = lane >> 4;
    const int c0 = blockIdx.x * 16;
    const int col = c0 + m;
    const bool colok = (DOUT % 16 == 0) || (col < DOUT);

    short8 bfrag[8];
#pragma unroll
    for (int s = 0; s < 8; ++s) {
#pragma unroll
        for (int j = 0; j < 8; ++j) {
            int k = s * 32 + quad * 8 + j;
            bfrag[s][j] = colok ? (short)W[(size_t)k * DOUT + col] : (short)0;
        }
    }

    const int step = gridDim.y * 4;
    for (int rt = blockIdx.y * 4 + wave; rt < N_NODES / 16; rt += step) {
        const int r0 = rt * 16;
        floatx4 acc = {0.f, 0.f, 0.f, 0.f};
        const ushort* arow = A + (size_t)(r0 + m) * 256 + quad * 8;
#pragma unroll
        for (int s = 0; s < 8; ++s) {
            short8 af = *(const short8*)(arow + s * 32);
            acc = __builtin_amdgcn_mfma_f32_16x16x32_bf16(af, bfrag[s], acc, 0, 0, 0);
        }
        if (colok) {
#pragma unroll
            for (int r = 0; r < 4; ++r) {
                int row = r0 + quad * 4 + r;
                float v = acc[r] * dinv[row];
                if (F32OUT) ((float*)T)[(size_t)row * DOUT + col] = v;
                else        ((ushort*)T)[(size_t)row * DOUT + col] = f2bf(v);
            }
        }
    }
}

// ---------------- Aggregation (width 256): H[i] = relu(dinv[i]*(T[i] + sum_nbr T[s]) + b) ----------------

__global__ __launch_bounds__(256)
void agg256_kernel(const ushort* __restrict__ T,
                   const int* __restrict__ csr, const int* __restrict__ offs,
                   const int* __restrict__ cnt, const float* __restrict__ dinv,
                   const ushort* __restrict__ bias,
                   ushort* __restrict__ H) {
    const int node = blockIdx.x * 4 + (threadIdx.x >> 6);
    const int lane = threadIdx.x & 63;
    const int start = offs[node];
    const int count = cnt[node];
    const float di = dinv[node];

    const ushort* base = T + lane * 4;
    ull self = *(const ull*)(base + (size_t)node * 256);
    float a0 = bf2f((ushort)self);
    float a1 = bf2f((ushort)(self >> 16));
    float a2 = bf2f((ushort)(self >> 32));
    float a3 = bf2f((ushort)(self >> 48));

    int idxv = 0;
    for (int j = 0; j < count; ++j) {
        if ((j & 63) == 0) {
            int a = start + j + lane;
            idxv = (a < start + count) ? csr[a] : 0;
        }
        int s = __shfl(idxv, j & 63);
        ull row = *(const ull*)(base + (size_t)s * 256);
        a0 += bf2f((ushort)row);
        a1 += bf2f((ushort)(row >> 16));
        a2 += bf2f((ushort)(row >> 32));
        a3 += bf2f((ushort)(row >> 48));
    }

    ull b4 = *(const ull*)(bias + lane * 4);
    float v0 = fmaxf(a0 * di + bf2f((ushort)b4), 0.f);
    float v1 = fmaxf(a1 * di + bf2f((ushort)(b4 >> 16)), 0.f);
    float v2 = fmaxf(a2 * di + bf2f((ushort)(b4 >> 32)), 0.f);
    float v3 = fmaxf(a3 * di + bf2f((ushort)(b4 >> 48)), 0.f);
    ull pack = (ull)f2bf(v0) | ((ull)f2bf(v1) << 16) | ((ull)f2bf(v2) << 32) | ((ull)f2bf(v3) << 48);
    *(ull*)(H + (size_t)node * 256 + lane * 4) = pack;
}

// ---------------- Aggregation (width 40, fp32 T) -> fp32 logits ----------------

__global__ __launch_bounds__(256)
void agg40_kernel(const float* __restrict__ T,
                  const int* __restrict__ csr, const int* __restrict__ offs,
                  const int* __restrict__ cnt, const float* __restrict__ dinv,
                  const ushort* __restrict__ bias,
                  float* __restrict__ logits) {
    const int node = blockIdx.x * 4 + (threadIdx.x >> 6);
    const int lane = threadIdx.x & 63;
    const int start = offs[node];
    const int count = cnt[node];
    const float di = dinv[node];

    float acc = (lane < NCLS) ? T[(size_t)node * NCLS + lane] : 0.f;
    int idxv = 0;
    for (int j = 0; j < count; ++j) {
        if ((j & 63) == 0) {
            int a = start + j + lane;
            idxv = (a < start + count) ? csr[a] : 0;
        }
        int s = __shfl(idxv, j & 63);
        if (lane < NCLS) acc += T[(size_t)s * NCLS + lane];
    }
    if (lane < NCLS)
        logits[(size_t)node * NCLS + lane] = acc * di + bf2f(bias[lane]);
}

// ---------------- log_softmax + write both outputs (fp32 or bf16 per flag) ----------------

__global__ __launch_bounds__(256)
void softmax_kernel(const float* __restrict__ logits, void* __restrict__ out,
                    const int* __restrict__ flags) {
    const int node = blockIdx.x * 4 + (threadIdx.x >> 6);
    const int lane = threadIdx.x & 63;
    float l = (lane < NCLS) ? logits[(size_t)node * NCLS + lane] : -INFINITY;
    float mx = l;
#pragma unroll
    for (int o = 32; o > 0; o >>= 1) mx = fmaxf(mx, __shfl_xor(mx, o));
    float e = (lane < NCLS) ? __expf(l - mx) : 0.f;
    float sum = e;
#pragma unroll
    for (int o = 32; o > 0; o >>= 1) sum += __shfl_xor(sum, o);
    float ls = l - mx - __logf(sum);
    if (lane < NCLS) {
        size_t i0 = (size_t)node * NCLS + lane;
        size_t i1 = (size_t)N_NODES * NCLS + i0;
        if (flags[0]) {  // fp32 output
            ((float*)out)[i0] = ls;
            ((float*)out)[i1] = l;
        } else {
            ((ushort*)out)[i0] = f2bf(ls);
            ((ushort*)out)[i1] = f2bf(l);
        }
    }
}

// ---------------- host ----------------

static inline size_t alup(size_t x) { return (x + 255) & ~(size_t)255; }

extern "C" void kernel_launch(void* const* d_in, const int* in_sizes, int n_in,
                              void* d_out, int out_size, void* d_ws, size_t ws_size,
                              hipStream_t stream) {
    const void* x  = d_in[0];
    const void* ei = d_in[1];
    const void* Wraw[5] = { d_in[2], d_in[4], d_in[6], d_in[8], d_in[10] };
    const void* Braw[5] = { d_in[3], d_in[5], d_in[7], d_in[9], d_in[11] };

    char* w = (char*)d_ws;
    int* flags   = (int*)w;           w += alup(16);
    float* dinv  = (float*)w;         w += alup(N_NODES * 4);
    int* cnt     = (int*)w;           w += alup(N_NODES * 4);
    int* offs    = (int*)w;           w += alup(N_NODES * 4);
    int* woff    = (int*)w;           w += alup(N_NODES * 4);
    int* src32   = (int*)w;           w += alup(N_EDGES * 4);
    int* dst32   = (int*)w;           w += alup(N_EDGES * 4);
    int* csr     = (int*)w;           w += alup(N_EDGES * 4);
    ushort* xb   = (ushort*)w;        w += alup((size_t)N_NODES * HDIM * 2);
    ushort* wb[5]; ushort* bb[5];
    for (int l = 0; l < 5; ++l) {
        int wn = (l < 4) ? HDIM * HDIM : HDIM * NCLS;
        int bn = (l < 4) ? HDIM : NCLS;
        wb[l] = (ushort*)w; w += alup((size_t)wn * 2);
        bb[l] = (ushort*)w; w += alup((size_t)bn * 2);
    }
    ushort* tbuf = (ushort*)w;        w += alup((size_t)N_NODES * HDIM * 2);
    ushort* hbuf = (ushort*)w;        w += alup((size_t)N_NODES * HDIM * 2);
    float* t5    = (float*)w;         w += alup((size_t)N_NODES * NCLS * 4);
    float* logits = (float*)w;        w += alup((size_t)N_NODES * NCLS * 4);

    const int nblk = (N_NODES + 255) / 256;   // 40
    const int eblk = (N_EDGES + 255) / 256;   // 1250

    detect_kernel<<<1, 64, 0, stream>>>(x, ei, flags);

    // convert all float tensors to bf16
    cvt_kernel<<<(N_NODES * HDIM + 255) / 256, 256, 0, stream>>>(x, xb, N_NODES * HDIM, flags);
    for (int l = 0; l < 5; ++l) {
        int wn = (l < 4) ? HDIM * HDIM : HDIM * NCLS;
        int bn = (l < 4) ? HDIM : NCLS;
        cvt_kernel<<<(wn + 255) / 256, 256, 0, stream>>>(Wraw[l], wb[l], wn, flags);
        cvt_kernel<<<(bn + 255) / 256, 256, 0, stream>>>(Braw[l], bb[l], bn, flags);
    }

    edges_kernel<<<eblk, 256, 0, stream>>>(ei, flags, src32, dst32);
    zero_cnt_kernel<<<nblk, 256, 0, stream>>>(cnt);
    count_kernel<<<eblk, 256, 0, stream>>>(dst32, cnt);
    dinv_kernel<<<nblk, 256, 0, stream>>>(cnt, dinv);
    scan_kernel<<<1, 1024, 0, stream>>>(cnt, offs, woff);
    fill_kernel<<<eblk, 256, 0, stream>>>(src32, dst32, woff, csr);

    const int aggblk = N_NODES / 4;  // 2500

    gemm_kernel<HDIM, 0><<<dim3(16, 39), 256, 0, stream>>>(xb, wb[0], dinv, tbuf);
    agg256_kernel<<<aggblk, 256, 0, stream>>>(tbuf, csr, offs, cnt, dinv, bb[0], hbuf);
    for (int l = 1; l < 4; ++l) {
        gemm_kernel<HDIM, 0><<<dim3(16, 39), 256, 0, stream>>>(hbuf, wb[l], dinv, tbuf);
        agg256_kernel<<<aggblk, 256, 0, stream>>>(tbuf, csr, offs, cnt, dinv, bb[l], hbuf);
    }
    gemm_kernel<NCLS, 1><<<dim3(3, 80), 256, 0, stream>>>(hbuf, wb[4], dinv, t5);
    agg40_kernel<<<aggblk, 256, 0, stream>>>(t5, csr, offs, cnt, dinv, bb[4], logits);
    softmax_kernel<<<aggblk, 256, 0, stream>>>(logits, d_out, flags);
}

// Round 3
// 288.215 us; speedup vs baseline: 1.3362x; 1.3362x over previous
//
#include <hip/hip_runtime.h>
#include <hip/hip_bf16.h>

#define N_NODES 10000
#define N_EDGES 320000
#define HDIM    256
#define NCLS    40

typedef __attribute__((ext_vector_type(8))) short short8;
typedef __attribute__((ext_vector_type(4))) float floatx4;
typedef unsigned long long ull;
typedef unsigned short ushort;

__device__ __forceinline__ float bf2f(ushort u) {
    union { unsigned int i; float f; } v; v.i = ((unsigned int)u) << 16; return v.f;
}
__device__ __forceinline__ ushort f2bf(float f) {
    __hip_bfloat16 h = __float2bfloat16(f);
    return *reinterpret_cast<ushort*>(&h);
}

// ---------------- dtype detection: flags[0]=fp32 floats, flags[1]=int64 edges ----------------

__global__ void detect_kernel(const void* x, const void* ei, int* flags) {
    const int lane = threadIdx.x & 63;
    const ushort* u = (const ushort*)x;
    int e = (u[2 * lane] >> 7) & 0xFF;          // even halfword: fp32 low-mantissa (uniform) vs bf16 value
    ull badmask = __ballot(e < 100 || e > 140); // bf16 of N(0,1): exp in [100,140]
    const int* ii = (const int*)ei;
    ull oddnz = __ballot(ii[2 * lane + 1] != 0);
    if (lane == 0) {
        flags[0] = (__popcll(badmask) >= 8) ? 1 : 0;
        flags[1] = (oddnz == 0) ? 1 : 0;
    }
}

// ---------------- fused prep: x->bf16 (vec4), W/b->bf16, edges->int32, zero cnt ----------------

struct PrepArgs {
    const void* x;
    const void* ei;
    const void* wsrc[10];
    ushort* wdst[10];
    int woffs[11];
    ushort* xb;
    int* src32;
    int* dst32;
    int* cnt;
    const int* flags;
};

#define PREP_XB 2500
#define PREP_WB 1069
#define PREP_EB 1250
#define PREP_ZB 40
#define PREP_TOTAL (PREP_XB + PREP_WB + PREP_EB + PREP_ZB)
#define WTOT 273448

__global__ __launch_bounds__(256)
void prep_kernel(PrepArgs a) {
    const int b = blockIdx.x;
    const int f32 = a.flags[0];
    if (b < PREP_XB) {
        int i4 = b * 256 + threadIdx.x;        // vec4 index; 2500*256*4 == 2,560,000 exactly
        if (f32) {
            float4 v = ((const float4*)a.x)[i4];
            ull p = (ull)f2bf(v.x) | ((ull)f2bf(v.y) << 16) |
                    ((ull)f2bf(v.z) << 32) | ((ull)f2bf(v.w) << 48);
            ((ull*)a.xb)[i4] = p;
        } else {
            ((ull*)a.xb)[i4] = ((const ull*)a.x)[i4];
        }
    } else if (b < PREP_XB + PREP_WB) {
        int i = (b - PREP_XB) * 256 + threadIdx.x;
        if (i < WTOT) {
            int t = 0;
#pragma unroll
            for (int k = 1; k < 10; ++k) t += (i >= a.woffs[k]);
            int local = i - a.woffs[t];
            ushort v;
            if (f32) v = f2bf(((const float*)a.wsrc[t])[local]);
            else     v = ((const ushort*)a.wsrc[t])[local];
            a.wdst[t][local] = v;
        }
    } else if (b < PREP_XB + PREP_WB + PREP_EB) {
        int e = (b - PREP_XB - PREP_WB) * 256 + threadIdx.x;
        const int* ii = (const int*)a.ei;
        int s, d;
        if (a.flags[1]) { s = ii[2 * e]; d = ii[2 * (N_EDGES + e)]; }
        else            { s = ii[e];     d = ii[N_EDGES + e]; }
        a.src32[e] = ((unsigned)s < N_NODES) ? s : 0;
        a.dst32[e] = ((unsigned)d < N_NODES) ? d : 0;
    } else {
        int i = (b - PREP_XB - PREP_WB - PREP_EB) * 256 + threadIdx.x;
        if (i < N_NODES) a.cnt[i] = 0;
    }
}

// ---------------- CSR build ----------------

__global__ void count_kernel(const int* __restrict__ dst, int* __restrict__ cnt) {
    int e = blockIdx.x * 256 + threadIdx.x;
    if (e < N_EDGES) atomicAdd(&cnt[dst[e]], 1);
}

__global__ __launch_bounds__(1024)
void scan_dinv_kernel(const int* __restrict__ cnt, int* __restrict__ offs,
                      int* __restrict__ woff, float* __restrict__ dinv) {
    __shared__ int part[1024];
    const int t = threadIdx.x;
    const int CH = (N_NODES + 1023) / 1024;  // 10
    const int base = t * CH;
    int s = 0;
    for (int j = 0; j < CH; ++j) {
        int i = base + j;
        if (i < N_NODES) s += cnt[i];
    }
    part[t] = s;
    __syncthreads();
    for (int off = 1; off < 1024; off <<= 1) {
        int v = 0;
        if (t >= off) v = part[t - off];
        __syncthreads();
        part[t] += v;
        __syncthreads();
    }
    int run = (t == 0) ? 0 : part[t - 1];
    for (int j = 0; j < CH; ++j) {
        int i = base + j;
        if (i < N_NODES) {
            int c = cnt[i];
            offs[i] = run;
            woff[i] = run;
            dinv[i] = rsqrtf((float)c + 1.0f);
            run += c;
        }
    }
}

__global__ void fill_kernel(const int* __restrict__ src, const int* __restrict__ dst,
                            int* __restrict__ woff, int* __restrict__ csr) {
    int e = blockIdx.x * 256 + threadIdx.x;
    if (e < N_EDGES) {
        int d = dst[e];
        int p = atomicAdd(&woff[d], 1);
        csr[p] = src[e];
    }
}

// ---------------- GEMM 256-wide: 2 col-tiles per wave, grid (8, 39) ----------------
// T[r][c] = (sum_k A[r][k]*W[k][c]) * dinv[r], bf16 out

__global__ __launch_bounds__(256)
void gemm256_kernel(const ushort* __restrict__ A, const ushort* __restrict__ W,
                    const float* __restrict__ dinv, ushort* __restrict__ T) {
    const int lane = threadIdx.x & 63;
    const int wave = threadIdx.x >> 6;
    const int m = lane & 15;
    const int quad = lane >> 4;
    const int c0 = blockIdx.x * 32;

    short8 bfrag[2][8];
#pragma unroll
    for (int t = 0; t < 2; ++t)
#pragma unroll
        for (int s = 0; s < 8; ++s)
#pragma unroll
            for (int j = 0; j < 8; ++j)
                bfrag[t][s][j] = (short)W[(size_t)(s * 32 + quad * 8 + j) * 256 + c0 + t * 16 + m];

    const int step = gridDim.y * 4;
    for (int rt = blockIdx.y * 4 + wave; rt < N_NODES / 16; rt += step) {
        const int r0 = rt * 16;
        floatx4 acc0 = {0.f, 0.f, 0.f, 0.f};
        floatx4 acc1 = {0.f, 0.f, 0.f, 0.f};
        const ushort* arow = A + (size_t)(r0 + m) * 256 + quad * 8;
#pragma unroll
        for (int s = 0; s < 8; ++s) {
            short8 af = *(const short8*)(arow + s * 32);
            acc0 = __builtin_amdgcn_mfma_f32_16x16x32_bf16(af, bfrag[0][s], acc0, 0, 0, 0);
            acc1 = __builtin_amdgcn_mfma_f32_16x16x32_bf16(af, bfrag[1][s], acc1, 0, 0, 0);
        }
#pragma unroll
        for (int r = 0; r < 4; ++r) {
            int row = r0 + quad * 4 + r;
            float di = dinv[row];
            T[(size_t)row * 256 + c0 + m]      = f2bf(acc0[r] * di);
            T[(size_t)row * 256 + c0 + 16 + m] = f2bf(acc1[r] * di);
        }
    }
}

// ---------------- GEMM 40-wide -> fp32 T5, grid (3, 80) ----------------

__global__ __launch_bounds__(256)
void gemm40_kernel(const ushort* __restrict__ A, const ushort* __restrict__ W,
                   const float* __restrict__ dinv, float* __restrict__ T) {
    const int lane = threadIdx.x & 63;
    const int wave = threadIdx.x >> 6;
    const int m = lane & 15;
    const int quad = lane >> 4;
    const int col = blockIdx.x * 16 + m;
    const bool colok = col < NCLS;

    short8 bfrag[8];
#pragma unroll
    for (int s = 0; s < 8; ++s)
#pragma unroll
        for (int j = 0; j < 8; ++j)
            bfrag[s][j] = colok ? (short)W[(size_t)(s * 32 + quad * 8 + j) * NCLS + col] : (short)0;

    const int step = gridDim.y * 4;
    for (int rt = blockIdx.y * 4 + wave; rt < N_NODES / 16; rt += step) {
        const int r0 = rt * 16;
        floatx4 acc = {0.f, 0.f, 0.f, 0.f};
        const ushort* arow = A + (size_t)(r0 + m) * 256 + quad * 8;
#pragma unroll
        for (int s = 0; s < 8; ++s) {
            short8 af = *(const short8*)(arow + s * 32);
            acc = __builtin_amdgcn_mfma_f32_16x16x32_bf16(af, bfrag[s], acc, 0, 0, 0);
        }
        if (colok) {
#pragma unroll
            for (int r = 0; r < 4; ++r) {
                int row = r0 + quad * 4 + r;
                T[(size_t)row * NCLS + col] = acc[r] * dinv[row];
            }
        }
    }
}

// ---------------- Aggregation 256-wide, 4-deep pipelined gathers ----------------

#define ACC8(r)                                  \
    a0 += bf2f((ushort)(r));                     \
    a1 += bf2f((ushort)((r) >> 16));             \
    a2 += bf2f((ushort)((r) >> 32));             \
    a3 += bf2f((ushort)((r) >> 48));

__global__ __launch_bounds__(256)
void agg256_kernel(const ushort* __restrict__ T,
                   const int* __restrict__ csr, const int* __restrict__ offs,
                   const int* __restrict__ cnt, const float* __restrict__ dinv,
                   const ushort* __restrict__ bias,
                   ushort* __restrict__ H) {
    const int node = blockIdx.x * 4 + (threadIdx.x >> 6);
    const int lane = threadIdx.x & 63;
    const int start = offs[node];
    const int count = cnt[node];
    const float di = dinv[node];

    const ushort* base = T + lane * 4;
    ull self = *(const ull*)(base + (size_t)node * 256);
    float a0 = bf2f((ushort)self);
    float a1 = bf2f((ushort)(self >> 16));
    float a2 = bf2f((ushort)(self >> 32));
    float a3 = bf2f((ushort)(self >> 48));

    for (int bj = 0; bj < count; bj += 64) {
        int mrem = count - bj;
        int mm = mrem < 64 ? mrem : 64;
        int idxv = (lane < mm) ? csr[start + bj + lane] : 0;
        int jj = 0;
        for (; jj + 4 <= mm; jj += 4) {
            int s0 = __shfl(idxv, jj + 0);
            int s1 = __shfl(idxv, jj + 1);
            int s2 = __shfl(idxv, jj + 2);
            int s3 = __shfl(idxv, jj + 3);
            ull r0 = *(const ull*)(base + (size_t)s0 * 256);
            ull r1 = *(const ull*)(base + (size_t)s1 * 256);
            ull r2 = *(const ull*)(base + (size_t)s2 * 256);
            ull r3 = *(const ull*)(base + (size_t)s3 * 256);
            ACC8(r0); ACC8(r1); ACC8(r2); ACC8(r3);
        }
        for (; jj < mm; ++jj) {
            int s = __shfl(idxv, jj);
            ull r = *(const ull*)(base + (size_t)s * 256);
            ACC8(r);
        }
    }

    ull b4 = *(const ull*)(bias + lane * 4);
    float v0 = fmaxf(a0 * di + bf2f((ushort)b4), 0.f);
    float v1 = fmaxf(a1 * di + bf2f((ushort)(b4 >> 16)), 0.f);
    float v2 = fmaxf(a2 * di + bf2f((ushort)(b4 >> 32)), 0.f);
    float v3 = fmaxf(a3 * di + bf2f((ushort)(b4 >> 48)), 0.f);
    ull pack = (ull)f2bf(v0) | ((ull)f2bf(v1) << 16) | ((ull)f2bf(v2) << 32) | ((ull)f2bf(v3) << 48);
    *(ull*)(H + (size_t)node * 256 + lane * 4) = pack;
}

// ---------------- Aggregation 40-wide + log_softmax + output writes, fused ----------------

__global__ __launch_bounds__(256)
void aggsoft_kernel(const float* __restrict__ T,
                    const int* __restrict__ csr, const int* __restrict__ offs,
                    const int* __restrict__ cnt, const float* __restrict__ dinv,
                    const ushort* __restrict__ bias,
                    void* __restrict__ out, const int* __restrict__ flags) {
    const int node = blockIdx.x * 4 + (threadIdx.x >> 6);
    const int lane = threadIdx.x & 63;
    const int start = offs[node];
    const int count = cnt[node];
    const float di = dinv[node];

    float acc = (lane < NCLS) ? T[(size_t)node * NCLS + lane] : 0.f;
    for (int bj = 0; bj < count; bj += 64) {
        int mrem = count - bj;
        int mm = mrem < 64 ? mrem : 64;
        int idxv = (lane < mm) ? csr[start + bj + lane] : 0;
        int jj = 0;
        for (; jj + 4 <= mm; jj += 4) {
            int s0 = __shfl(idxv, jj + 0);
            int s1 = __shfl(idxv, jj + 1);
            int s2 = __shfl(idxv, jj + 2);
            int s3 = __shfl(idxv, jj + 3);
            if (lane < NCLS) {
                float t0 = T[(size_t)s0 * NCLS + lane];
                float t1 = T[(size_t)s1 * NCLS + lane];
                float t2 = T[(size_t)s2 * NCLS + lane];
                float t3 = T[(size_t)s3 * NCLS + lane];
                acc += t0 + t1 + t2 + t3;
            }
        }
        for (; jj < mm; ++jj) {
            int s = __shfl(idxv, jj);
            if (lane < NCLS) acc += T[(size_t)s * NCLS + lane];
        }
    }

    float l = (lane < NCLS) ? (acc * di + bf2f(bias[lane])) : -INFINITY;
    float mx = l;
#pragma unroll
    for (int o = 32; o > 0; o >>= 1) mx = fmaxf(mx, __shfl_xor(mx, o));
    float e = (lane < NCLS) ? __expf(l - mx) : 0.f;
    float sum = e;
#pragma unroll
    for (int o = 32; o > 0; o >>= 1) sum += __shfl_xor(sum, o);
    float ls = l - mx - __logf(sum);
    if (lane < NCLS) {
        size_t i0 = (size_t)node * NCLS + lane;
        size_t i1 = (size_t)N_NODES * NCLS + i0;
        if (flags[0]) {
            ((float*)out)[i0] = ls;
            ((float*)out)[i1] = l;
        } else {
            ((ushort*)out)[i0] = f2bf(ls);
            ((ushort*)out)[i1] = f2bf(l);
        }
    }
}

// ---------------- host ----------------

static inline size_t alup(size_t x) { return (x + 255) & ~(size_t)255; }

extern "C" void kernel_launch(void* const* d_in, const int* in_sizes, int n_in,
                              void* d_out, int out_size, void* d_ws, size_t ws_size,
                              hipStream_t stream) {
    char* w = (char*)d_ws;
    int* flags   = (int*)w;           w += alup(16);
    float* dinv  = (float*)w;         w += alup(N_NODES * 4);
    int* cnt     = (int*)w;           w += alup(N_NODES * 4);
    int* offs    = (int*)w;           w += alup(N_NODES * 4);
    int* woff    = (int*)w;           w += alup(N_NODES * 4);
    int* src32   = (int*)w;           w += alup(N_EDGES * 4);
    int* dst32   = (int*)w;           w += alup(N_EDGES * 4);
    int* csr     = (int*)w;           w += alup(N_EDGES * 4);
    ushort* xb   = (ushort*)w;        w += alup((size_t)N_NODES * HDIM * 2);
    ushort* wb[5]; ushort* bb[5];
    for (int l = 0; l < 5; ++l) {
        int wn = (l < 4) ? HDIM * HDIM : HDIM * NCLS;
        int bn = (l < 4) ? HDIM : NCLS;
        wb[l] = (ushort*)w; w += alup((size_t)wn * 2);
        bb[l] = (ushort*)w; w += alup((size_t)bn * 2);
    }
    ushort* tbuf = (ushort*)w;        w += alup((size_t)N_NODES * HDIM * 2);
    ushort* hbuf = (ushort*)w;        w += alup((size_t)N_NODES * HDIM * 2);
    float* t5    = (float*)w;         w += alup((size_t)N_NODES * NCLS * 4);

    detect_kernel<<<1, 64, 0, stream>>>(d_in[0], d_in[1], flags);

    PrepArgs pa;
    pa.x = d_in[0];
    pa.ei = d_in[1];
    int sizes[10] = { HDIM * HDIM, HDIM, HDIM * HDIM, HDIM, HDIM * HDIM, HDIM,
                      HDIM * HDIM, HDIM, HDIM * NCLS, NCLS };
    int run = 0;
    for (int t = 0; t < 10; ++t) {
        pa.wsrc[t] = d_in[2 + t];
        pa.wdst[t] = (t & 1) ? bb[t >> 1] : wb[t >> 1];
        pa.woffs[t] = run;
        run += sizes[t];
    }
    pa.woffs[10] = run;  // == WTOT
    pa.xb = xb; pa.src32 = src32; pa.dst32 = dst32; pa.cnt = cnt; pa.flags = flags;

    prep_kernel<<<PREP_TOTAL, 256, 0, stream>>>(pa);

    const int eblk = (N_EDGES + 255) / 256;   // 1250
    count_kernel<<<eblk, 256, 0, stream>>>(dst32, cnt);
    scan_dinv_kernel<<<1, 1024, 0, stream>>>(cnt, offs, woff, dinv);
    fill_kernel<<<eblk, 256, 0, stream>>>(src32, dst32, woff, csr);

    const int aggblk = N_NODES / 4;  // 2500

    gemm256_kernel<<<dim3(8, 39), 256, 0, stream>>>(xb, wb[0], dinv, tbuf);
    agg256_kernel<<<aggblk, 256, 0, stream>>>(tbuf, csr, offs, cnt, dinv, bb[0], hbuf);
    for (int l = 1; l < 4; ++l) {
        gemm256_kernel<<<dim3(8, 39), 256, 0, stream>>>(hbuf, wb[l], dinv, tbuf);
        agg256_kernel<<<aggblk, 256, 0, stream>>>(tbuf, csr, offs, cnt, dinv, bb[l], hbuf);
    }
    gemm40_kernel<<<dim3(3, 80), 256, 0, stream>>>(hbuf, wb[4], dinv, t5);
    aggsoft_kernel<<<aggblk, 256, 0, stream>>>(t5, csr, offs, cnt, dinv, bb[4], d_out, flags);
}

// Round 4
// 274.158 us; speedup vs baseline: 1.4047x; 1.0513x over previous
//
#include <hip/hip_runtime.h>
#include <hip/hip_bf16.h>

#define N_NODES 10000
#define N_EDGES 320000
#define HDIM    256
#define NCLS    40

typedef __attribute__((ext_vector_type(8))) short short8;
typedef __attribute__((ext_vector_type(4))) float floatx4;
typedef unsigned long long ull;
typedef unsigned short ushort;

__device__ __forceinline__ float bf2f(ushort u) {
    union { unsigned int i; float f; } v; v.i = ((unsigned int)u) << 16; return v.f;
}
__device__ __forceinline__ ushort f2bf(float f) {
    __hip_bfloat16 h = __float2bfloat16(f);
    return *reinterpret_cast<ushort*>(&h);
}

// ---------------- dtype detection: flags[0]=fp32 floats, flags[1]=int64 edges ----------------

__global__ void detect_kernel(const void* x, const void* ei, int* flags) {
    const int lane = threadIdx.x & 63;
    const ushort* u = (const ushort*)x;
    int e = (u[2 * lane] >> 7) & 0xFF;
    ull badmask = __ballot(e < 100 || e > 140);
    const int* ii = (const int*)ei;
    ull oddnz = __ballot(ii[2 * lane + 1] != 0);
    if (lane == 0) {
        flags[0] = (__popcll(badmask) >= 8) ? 1 : 0;
        flags[1] = (oddnz == 0) ? 1 : 0;
    }
}

// ---------------- fused prep ----------------

struct PrepArgs {
    const void* x;
    const void* ei;
    const void* wsrc[10];
    ushort* wdst[10];
    int woffs[11];
    ushort* xb;
    int* src32;
    int* dst32;
    int* cnt;
    ushort* tbuf;   // sentinel row zeroing
    ushort* hbuf;
    const int* flags;
};

#define PREP_XB 2500
#define PREP_WB 1069
#define PREP_EB 1250
#define PREP_ZB 40
#define PREP_SB 1
#define PREP_TOTAL (PREP_XB + PREP_WB + PREP_EB + PREP_ZB + PREP_SB)
#define WTOT 273448

__global__ __launch_bounds__(256)
void prep_kernel(PrepArgs a) {
    const int b = blockIdx.x;
    const int f32 = a.flags[0];
    if (b < PREP_XB) {
        int i4 = b * 256 + threadIdx.x;   // 2500*256*4 == 2,560,000 exactly
        if (f32) {
            float4 v = ((const float4*)a.x)[i4];
            ull p = (ull)f2bf(v.x) | ((ull)f2bf(v.y) << 16) |
                    ((ull)f2bf(v.z) << 32) | ((ull)f2bf(v.w) << 48);
            ((ull*)a.xb)[i4] = p;
        } else {
            ((ull*)a.xb)[i4] = ((const ull*)a.x)[i4];
        }
    } else if (b < PREP_XB + PREP_WB) {
        int i = (b - PREP_XB) * 256 + threadIdx.x;
        if (i < WTOT) {
            int t = 0;
#pragma unroll
            for (int k = 1; k < 10; ++k) t += (i >= a.woffs[k]);
            int local = i - a.woffs[t];
            ushort v;
            if (f32) v = f2bf(((const float*)a.wsrc[t])[local]);
            else     v = ((const ushort*)a.wsrc[t])[local];
            a.wdst[t][local] = v;
        }
    } else if (b < PREP_XB + PREP_WB + PREP_EB) {
        int e = (b - PREP_XB - PREP_WB) * 256 + threadIdx.x;
        const int* ii = (const int*)a.ei;
        int s, d;
        if (a.flags[1]) { s = ii[2 * e]; d = ii[2 * (N_EDGES + e)]; }
        else            { s = ii[e];     d = ii[N_EDGES + e]; }
        a.src32[e] = ((unsigned)s < N_NODES) ? s : 0;
        a.dst32[e] = ((unsigned)d < N_NODES) ? d : 0;
    } else if (b < PREP_XB + PREP_WB + PREP_EB + PREP_ZB) {
        int i = (b - PREP_XB - PREP_WB - PREP_EB) * 256 + threadIdx.x;
        if (i < N_NODES) a.cnt[i] = 0;
    } else {
        // zero sentinel rows (row N_NODES) of tbuf and hbuf: 512 B each
        int t = threadIdx.x;
        if (t < 64)       ((ull*)(a.tbuf + (size_t)N_NODES * 256))[t] = 0;
        else if (t < 128) ((ull*)(a.hbuf + (size_t)N_NODES * 256))[t - 64] = 0;
    }
}

// ---------------- CSR build ----------------

__global__ void count_kernel(const int* __restrict__ dst, int* __restrict__ cnt) {
    int e = blockIdx.x * 256 + threadIdx.x;
    if (e < N_EDGES) atomicAdd(&cnt[dst[e]], 1);
}

__global__ __launch_bounds__(1024)
void scan_dinv_kernel(const int* __restrict__ cnt, int* __restrict__ offs,
                      int* __restrict__ woff, float* __restrict__ dinv) {
    __shared__ int part[1024];
    const int t = threadIdx.x;
    const int CH = (N_NODES + 1023) / 1024;  // 10
    const int base = t * CH;
    int s = 0;
    for (int j = 0; j < CH; ++j) {
        int i = base + j;
        if (i < N_NODES) s += cnt[i];
    }
    part[t] = s;
    __syncthreads();
    for (int off = 1; off < 1024; off <<= 1) {
        int v = 0;
        if (t >= off) v = part[t - off];
        __syncthreads();
        part[t] += v;
        __syncthreads();
    }
    int run = (t == 0) ? 0 : part[t - 1];
    for (int j = 0; j < CH; ++j) {
        int i = base + j;
        if (i < N_NODES) {
            int c = cnt[i];
            offs[i] = run;
            woff[i] = run;
            dinv[i] = rsqrtf((float)c + 1.0f);
            run += c;
        }
    }
}

__global__ void fill_kernel(const int* __restrict__ src, const int* __restrict__ dst,
                            int* __restrict__ woff, int* __restrict__ csr) {
    int e = blockIdx.x * 256 + threadIdx.x;
    if (e < N_EDGES) {
        int d = dst[e];
        int p = atomicAdd(&woff[d], 1);
        csr[p] = src[e];
    }
}

// ---------------- GEMM 256-wide: 2 col-tiles per wave, grid (8, 78) ----------------

__global__ __launch_bounds__(256)
void gemm256_kernel(const ushort* __restrict__ A, const ushort* __restrict__ W,
                    const float* __restrict__ dinv, ushort* __restrict__ T) {
    const int lane = threadIdx.x & 63;
    const int wave = threadIdx.x >> 6;
    const int m = lane & 15;
    const int quad = lane >> 4;
    const int c0 = blockIdx.x * 32;

    short8 bfrag[2][8];
#pragma unroll
    for (int t = 0; t < 2; ++t)
#pragma unroll
        for (int s = 0; s < 8; ++s)
#pragma unroll
            for (int j = 0; j < 8; ++j)
                bfrag[t][s][j] = (short)W[(size_t)(s * 32 + quad * 8 + j) * 256 + c0 + t * 16 + m];

    const int step = gridDim.y * 4;
    for (int rt = blockIdx.y * 4 + wave; rt < N_NODES / 16; rt += step) {
        const int r0 = rt * 16;
        floatx4 acc0 = {0.f, 0.f, 0.f, 0.f};
        floatx4 acc1 = {0.f, 0.f, 0.f, 0.f};
        const ushort* arow = A + (size_t)(r0 + m) * 256 + quad * 8;
#pragma unroll
        for (int s = 0; s < 8; ++s) {
            short8 af = *(const short8*)(arow + s * 32);
            acc0 = __builtin_amdgcn_mfma_f32_16x16x32_bf16(af, bfrag[0][s], acc0, 0, 0, 0);
            acc1 = __builtin_amdgcn_mfma_f32_16x16x32_bf16(af, bfrag[1][s], acc1, 0, 0, 0);
        }
#pragma unroll
        for (int r = 0; r < 4; ++r) {
            int row = r0 + quad * 4 + r;
            float di = dinv[row];
            T[(size_t)row * 256 + c0 + m]      = f2bf(acc0[r] * di);
            T[(size_t)row * 256 + c0 + 16 + m] = f2bf(acc1[r] * di);
        }
    }
}

// ---------------- GEMM 40-wide -> fp32 T5, grid (3, 80) ----------------

__global__ __launch_bounds__(256)
void gemm40_kernel(const ushort* __restrict__ A, const ushort* __restrict__ W,
                   const float* __restrict__ dinv, float* __restrict__ T) {
    const int lane = threadIdx.x & 63;
    const int wave = threadIdx.x >> 6;
    const int m = lane & 15;
    const int quad = lane >> 4;
    const int col = blockIdx.x * 16 + m;
    const bool colok = col < NCLS;

    short8 bfrag[8];
#pragma unroll
    for (int s = 0; s < 8; ++s)
#pragma unroll
        for (int j = 0; j < 8; ++j)
            bfrag[s][j] = colok ? (short)W[(size_t)(s * 32 + quad * 8 + j) * NCLS + col] : (short)0;

    const int step = gridDim.y * 4;
    for (int rt = blockIdx.y * 4 + wave; rt < N_NODES / 16; rt += step) {
        const int r0 = rt * 16;
        floatx4 acc = {0.f, 0.f, 0.f, 0.f};
        const ushort* arow = A + (size_t)(r0 + m) * 256 + quad * 8;
#pragma unroll
        for (int s = 0; s < 8; ++s) {
            short8 af = *(const short8*)(arow + s * 32);
            acc = __builtin_amdgcn_mfma_f32_16x16x32_bf16(af, bfrag[s], acc, 0, 0, 0);
        }
        if (colok) {
#pragma unroll
            for (int r = 0; r < 4; ++r) {
                int row = r0 + quad * 4 + r;
                T[(size_t)row * NCLS + col] = acc[r] * dinv[row];
            }
        }
    }
}

// ---------------- Aggregation 256-wide: dual-row 16B gathers ----------------
// Each half-wave (32 lanes) gathers a different neighbor row; lane q covers
// cols q*8..q*8+7 (16 B). Tail neighbor padded with sentinel zero-row N_NODES.

__device__ __forceinline__ void accum16(float* acc, int4 r) {
    int d[4] = {r.x, r.y, r.z, r.w};
#pragma unroll
    for (int k = 0; k < 4; ++k) {
        union { int i; float f; } lo, hi;
        lo.i = d[k] << 16;
        hi.i = d[k] & 0xffff0000;
        acc[2 * k]     += lo.f;
        acc[2 * k + 1] += hi.f;
    }
}

__global__ __launch_bounds__(256)
void agg256_kernel(const ushort* __restrict__ T,
                   const int* __restrict__ csr, const int* __restrict__ offs,
                   const int* __restrict__ cnt, const float* __restrict__ dinv,
                   const ushort* __restrict__ bias,
                   ushort* __restrict__ H) {
    const int node = blockIdx.x * 4 + (threadIdx.x >> 6);
    const int lane = threadIdx.x & 63;
    const int half = lane >> 5;
    const int q = lane & 31;
    const int start = offs[node];
    const int count = cnt[node];
    const float di = dinv[node];

    float acc[8];
    {
        int sinit = half ? N_NODES : node;
        int4 r = *(const int4*)(T + (size_t)sinit * 256 + q * 8);
#pragma unroll
        for (int k = 0; k < 4; ++k) {
            union { int i; float f; } lo, hi;
            int d = (&r.x)[k];
            lo.i = d << 16; hi.i = d & 0xffff0000;
            acc[2 * k] = lo.f; acc[2 * k + 1] = hi.f;
        }
    }

    for (int bj = 0; bj < count; bj += 64) {
        int mrem = count - bj;
        int mm = mrem < 64 ? mrem : 64;
        int idxv = (lane < mm) ? csr[start + bj + lane] : N_NODES;
        int j2 = 0;
        for (; j2 + 8 <= mm; j2 += 8) {
            int s0 = __shfl(idxv, j2 + half);
            int s1 = __shfl(idxv, j2 + 2 + half);
            int s2 = __shfl(idxv, j2 + 4 + half);
            int s3 = __shfl(idxv, j2 + 6 + half);
            int4 r0 = *(const int4*)(T + (size_t)s0 * 256 + q * 8);
            int4 r1 = *(const int4*)(T + (size_t)s1 * 256 + q * 8);
            int4 r2 = *(const int4*)(T + (size_t)s2 * 256 + q * 8);
            int4 r3 = *(const int4*)(T + (size_t)s3 * 256 + q * 8);
            accum16(acc, r0); accum16(acc, r1); accum16(acc, r2); accum16(acc, r3);
        }
        for (; j2 < mm; j2 += 2) {
            int s = __shfl(idxv, j2 + half);
            int4 r = *(const int4*)(T + (size_t)s * 256 + q * 8);
            accum16(acc, r);
        }
    }

#pragma unroll
    for (int i = 0; i < 8; ++i) acc[i] += __shfl_xor(acc[i], 32);

    if (half == 0) {
        int4 bv = *(const int4*)(bias + q * 8);
        int out_d[4];
#pragma unroll
        for (int k = 0; k < 4; ++k) {
            union { int i; float f; } lo, hi;
            int d = (&bv.x)[k];
            lo.i = d << 16; hi.i = d & 0xffff0000;
            float v0 = fmaxf(acc[2 * k] * di + lo.f, 0.f);
            float v1 = fmaxf(acc[2 * k + 1] * di + hi.f, 0.f);
            out_d[k] = (int)f2bf(v0) | ((int)f2bf(v1) << 16);
        }
        *(int4*)(H + (size_t)node * 256 + q * 8) = *(int4*)out_d;
    }
}

// ---------------- Aggregation 40-wide + log_softmax + output writes, fused ----------------

__global__ __launch_bounds__(256)
void aggsoft_kernel(const float* __restrict__ T,
                    const int* __restrict__ csr, const int* __restrict__ offs,
                    const int* __restrict__ cnt, const float* __restrict__ dinv,
                    const ushort* __restrict__ bias,
                    void* __restrict__ out, const int* __restrict__ flags) {
    const int node = blockIdx.x * 4 + (threadIdx.x >> 6);
    const int lane = threadIdx.x & 63;
    const int start = offs[node];
    const int count = cnt[node];
    const float di = dinv[node];

    float acc = (lane < NCLS) ? T[(size_t)node * NCLS + lane] : 0.f;
    for (int bj = 0; bj < count; bj += 64) {
        int mrem = count - bj;
        int mm = mrem < 64 ? mrem : 64;
        int idxv = (lane < mm) ? csr[start + bj + lane] : 0;
        int jj = 0;
        for (; jj + 4 <= mm; jj += 4) {
            int s0 = __shfl(idxv, jj + 0);
            int s1 = __shfl(idxv, jj + 1);
            int s2 = __shfl(idxv, jj + 2);
            int s3 = __shfl(idxv, jj + 3);
            if (lane < NCLS) {
                float t0 = T[(size_t)s0 * NCLS + lane];
                float t1 = T[(size_t)s1 * NCLS + lane];
                float t2 = T[(size_t)s2 * NCLS + lane];
                float t3 = T[(size_t)s3 * NCLS + lane];
                acc += t0 + t1 + t2 + t3;
            }
        }
        for (; jj < mm; ++jj) {
            int s = __shfl(idxv, jj);
            if (lane < NCLS) acc += T[(size_t)s * NCLS + lane];
        }
    }

    float l = (lane < NCLS) ? (acc * di + bf2f(bias[lane])) : -INFINITY;
    float mx = l;
#pragma unroll
    for (int o = 32; o > 0; o >>= 1) mx = fmaxf(mx, __shfl_xor(mx, o));
    float e = (lane < NCLS) ? __expf(l - mx) : 0.f;
    float sum = e;
#pragma unroll
    for (int o = 32; o > 0; o >>= 1) sum += __shfl_xor(sum, o);
    float ls = l - mx - __logf(sum);
    if (lane < NCLS) {
        size_t i0 = (size_t)node * NCLS + lane;
        size_t i1 = (size_t)N_NODES * NCLS + i0;
        if (flags[0]) {
            ((float*)out)[i0] = ls;
            ((float*)out)[i1] = l;
        } else {
            ((ushort*)out)[i0] = f2bf(ls);
            ((ushort*)out)[i1] = f2bf(l);
        }
    }
}

// ---------------- host ----------------

static inline size_t alup(size_t x) { return (x + 255) & ~(size_t)255; }

extern "C" void kernel_launch(void* const* d_in, const int* in_sizes, int n_in,
                              void* d_out, int out_size, void* d_ws, size_t ws_size,
                              hipStream_t stream) {
    char* w = (char*)d_ws;
    int* flags   = (int*)w;           w += alup(16);
    float* dinv  = (float*)w;         w += alup(N_NODES * 4);
    int* cnt     = (int*)w;           w += alup(N_NODES * 4);
    int* offs    = (int*)w;           w += alup(N_NODES * 4);
    int* woff    = (int*)w;           w += alup(N_NODES * 4);
    int* src32   = (int*)w;           w += alup(N_EDGES * 4);
    int* dst32   = (int*)w;           w += alup(N_EDGES * 4);
    int* csr     = (int*)w;           w += alup(N_EDGES * 4);
    ushort* xb   = (ushort*)w;        w += alup((size_t)N_NODES * HDIM * 2);
    ushort* wb[5]; ushort* bb[5];
    for (int l = 0; l < 5; ++l) {
        int wn = (l < 4) ? HDIM * HDIM : HDIM * NCLS;
        int bn = (l < 4) ? HDIM : NCLS;
        wb[l] = (ushort*)w; w += alup((size_t)wn * 2);
        bb[l] = (ushort*)w; w += alup((size_t)bn * 2);
    }
    ushort* tbuf = (ushort*)w;        w += alup((size_t)(N_NODES + 16) * HDIM * 2);
    ushort* hbuf = (ushort*)w;        w += alup((size_t)(N_NODES + 16) * HDIM * 2);
    float* t5    = (float*)w;         w += alup((size_t)N_NODES * NCLS * 4);

    detect_kernel<<<1, 64, 0, stream>>>(d_in[0], d_in[1], flags);

    PrepArgs pa;
    pa.x = d_in[0];
    pa.ei = d_in[1];
    int sizes[10] = { HDIM * HDIM, HDIM, HDIM * HDIM, HDIM, HDIM * HDIM, HDIM,
                      HDIM * HDIM, HDIM, HDIM * NCLS, NCLS };
    int run = 0;
    for (int t = 0; t < 10; ++t) {
        pa.wsrc[t] = d_in[2 + t];
        pa.wdst[t] = (t & 1) ? bb[t >> 1] : wb[t >> 1];
        pa.woffs[t] = run;
        run += sizes[t];
    }
    pa.woffs[10] = run;  // == WTOT
    pa.xb = xb; pa.src32 = src32; pa.dst32 = dst32; pa.cnt = cnt;
    pa.tbuf = tbuf; pa.hbuf = hbuf; pa.flags = flags;

    prep_kernel<<<PREP_TOTAL, 256, 0, stream>>>(pa);

    const int eblk = (N_EDGES + 255) / 256;   // 1250
    count_kernel<<<eblk, 256, 0, stream>>>(dst32, cnt);
    scan_dinv_kernel<<<1, 1024, 0, stream>>>(cnt, offs, woff, dinv);
    fill_kernel<<<eblk, 256, 0, stream>>>(src32, dst32, woff, csr);

    const int aggblk = N_NODES / 4;  // 2500

    gemm256_kernel<<<dim3(8, 78), 256, 0, stream>>>(xb, wb[0], dinv, tbuf);
    agg256_kernel<<<aggblk, 256, 0, stream>>>(tbuf, csr, offs, cnt, dinv, bb[0], hbuf);
    for (int l = 1; l < 4; ++l) {
        gemm256_kernel<<<dim3(8, 78), 256, 0, stream>>>(hbuf, wb[l], dinv, tbuf);
        agg256_kernel<<<aggblk, 256, 0, stream>>>(tbuf, csr, offs, cnt, dinv, bb[l], hbuf);
    }
    gemm40_kernel<<<dim3(3, 80), 256, 0, stream>>>(hbuf, wb[4], dinv, t5);
    aggsoft_kernel<<<aggblk, 256, 0, stream>>>(t5, csr, offs, cnt, dinv, bb[4], d_out, flags);
}